// Round 1
// baseline (467.005 us; speedup 1.0000x reference)
//
#include <hip/hip_runtime.h>
#include <math.h>

#define K_CB    32768
#define C_DIM   32
#define N_TOK   4096
#define KSLICES 32
#define KPER    (K_CB / KSLICES)   // 1024
#define OUT_N   (N_TOK * C_DIM)    // 131072

// ---------------------------------------------------------------------------
// Kernel A: codebook norms  ||e_k||^2  (also zero the loss accumulator cell,
// since the harness poisons d_out with 0xAA before every launch)
// ---------------------------------------------------------------------------
__global__ __launch_bounds__(256) void vq_cbnorm(const float* __restrict__ cb,
                                                 float* __restrict__ norms,
                                                 float* __restrict__ out) {
    int k = blockIdx.x * 256 + threadIdx.x;
    const float4* p = reinterpret_cast<const float4*>(cb + (size_t)k * C_DIM);
    float s = 0.f;
#pragma unroll
    for (int i = 0; i < 8; ++i) {
        float4 v = p[i];
        s += v.x * v.x + v.y * v.y + v.z * v.z + v.w * v.w;
    }
    norms[k] = s;
    if (k == 0) out[OUT_N] = 0.f;
}

// ---------------------------------------------------------------------------
// Kernel B: partial argmin.  One token per thread (z row in 32 VGPRs).
// Grid = (N_TOK/256 token-blocks) x (KSLICES k-slices).
// d' = ||e||^2 - 2 z.e   (the per-token ||z||^2 constant is dropped —
// argmin-equivalent).  Codes are read at wave-uniform addresses so the
// backend can scalarize them (s_load) and feed FMAs as SGPR operands.
// ---------------------------------------------------------------------------
__global__ __launch_bounds__(256) void vq_partial(const float* __restrict__ z,
                                                  const float* __restrict__ cb,
                                                  const float* __restrict__ cbnorm,
                                                  float* __restrict__ pdist,
                                                  int* __restrict__ pidx) {
    const int tb  = blockIdx.x & (N_TOK / 256 - 1);  // token block (0..15)
    const int ks  = blockIdx.x / (N_TOK / 256);      // k slice     (0..31)
    const int tok = tb * 256 + threadIdx.x;
    const int b   = tok >> 10;
    const int hw  = tok & 1023;

    // z[b][c][h][w]  ->  zf[tok][c] at  z + b*32768 + c*1024 + hw
    const float* zp = z + b * (C_DIM * 1024) + hw;
    float zr[C_DIM];
#pragma unroll
    for (int c = 0; c < C_DIM; ++c) zr[c] = zp[c * 1024];

    float best  = INFINITY;
    int   bestk = 0;

    const int k0 = ks * KPER;
    for (int k = k0; k < k0 + KPER; ++k) {
        const float4* e4 = reinterpret_cast<const float4*>(cb + (size_t)k * C_DIM);
        float d0 = 0.f, d1 = 0.f, d2 = 0.f, d3 = 0.f;
#pragma unroll
        for (int i = 0; i < 8; i += 4) {
            float4 a = e4[i + 0];
            float4 bq = e4[i + 1];
            float4 cq = e4[i + 2];
            float4 dq = e4[i + 3];
            d0 = fmaf(a.x,  zr[4*i + 0],  d0);
            d0 = fmaf(a.y,  zr[4*i + 1],  d0);
            d0 = fmaf(a.z,  zr[4*i + 2],  d0);
            d0 = fmaf(a.w,  zr[4*i + 3],  d0);
            d1 = fmaf(bq.x, zr[4*i + 4],  d1);
            d1 = fmaf(bq.y, zr[4*i + 5],  d1);
            d1 = fmaf(bq.z, zr[4*i + 6],  d1);
            d1 = fmaf(bq.w, zr[4*i + 7],  d1);
            d2 = fmaf(cq.x, zr[4*i + 8],  d2);
            d2 = fmaf(cq.y, zr[4*i + 9],  d2);
            d2 = fmaf(cq.z, zr[4*i + 10], d2);
            d2 = fmaf(cq.w, zr[4*i + 11], d2);
            d3 = fmaf(dq.x, zr[4*i + 12], d3);
            d3 = fmaf(dq.y, zr[4*i + 13], d3);
            d3 = fmaf(dq.z, zr[4*i + 14], d3);
            d3 = fmaf(dq.w, zr[4*i + 15], d3);
        }
        float dot = (d0 + d1) + (d2 + d3);
        float d   = fmaf(-2.0f, dot, cbnorm[k]);
        if (d < best) { best = d; bestk = k; }   // strict <  => first-occurrence
    }

    pdist[ks * N_TOK + tok] = best;
    pidx [ks * N_TOK + tok] = bestk;
}

// ---------------------------------------------------------------------------
// Kernel C: reduce slices, gather code, write zq (transposed back to BCHW),
// accumulate loss = 1.25 * mean((zq - z)^2) via one atomicAdd per block.
// ---------------------------------------------------------------------------
__global__ __launch_bounds__(256) void vq_finalize(const float* __restrict__ z,
                                                   const float* __restrict__ cb,
                                                   const float* __restrict__ pdist,
                                                   const int* __restrict__ pidx,
                                                   float* __restrict__ out) {
    const int tok = blockIdx.x * 256 + threadIdx.x;

    float best  = INFINITY;
    int   bestk = 0;
#pragma unroll
    for (int s = 0; s < KSLICES; ++s) {
        float d = pdist[s * N_TOK + tok];
        int   k = pidx [s * N_TOK + tok];
        if (d < best) { best = d; bestk = k; }   // ascending slices => lowest k wins ties
    }

    const float* e  = cb + (size_t)bestk * C_DIM;
    const int    b  = tok >> 10;
    const int    hw = tok & 1023;
    const float* zp = z   + b * (C_DIM * 1024) + hw;
    float*       op = out + b * (C_DIM * 1024) + hw;

    float lsum = 0.f;
#pragma unroll
    for (int c = 0; c < C_DIM; ++c) {
        float ec = e[c];
        float zc = zp[c * 1024];
        float df = ec - zc;
        lsum = fmaf(df, df, lsum);
        op[c * 1024] = ec;
    }

    // wave64 reduce, then cross-wave via LDS
#pragma unroll
    for (int off = 32; off > 0; off >>= 1) lsum += __shfl_down(lsum, off, 64);
    __shared__ float wsum[4];
    const int lane = threadIdx.x & 63;
    const int wid  = threadIdx.x >> 6;
    if (lane == 0) wsum[wid] = lsum;
    __syncthreads();
    if (threadIdx.x == 0) {
        float bsum = (wsum[0] + wsum[1]) + (wsum[2] + wsum[3]);
        atomicAdd(out + OUT_N, bsum * (1.25f / (float)OUT_N));
    }
}

// ---------------------------------------------------------------------------
extern "C" void kernel_launch(void* const* d_in, const int* in_sizes, int n_in,
                              void* d_out, int out_size, void* d_ws, size_t ws_size,
                              hipStream_t stream) {
    const float* z  = (const float*)d_in[0];
    const float* cb = (const float*)d_in[1];
    float* out = (float*)d_out;

    float* norms = (float*)d_ws;                    // 32768 f32   (128 KiB)
    float* pdist = norms + K_CB;                    // 32*4096 f32 (512 KiB)
    int*   pidx  = (int*)(pdist + KSLICES * N_TOK); // 32*4096 i32 (512 KiB)

    vq_cbnorm  <<<K_CB / 256, 256, 0, stream>>>(cb, norms, out);
    vq_partial <<<(N_TOK / 256) * KSLICES, 256, 0, stream>>>(z, cb, norms, pdist, pidx);
    vq_finalize<<<N_TOK / 256, 256, 0, stream>>>(z, cb, pdist, pidx, out);
}

// Round 4
// 199.600 us; speedup vs baseline: 2.3397x; 2.3397x over previous
//
#include <hip/hip_runtime.h>
#include <math.h>

#define K_CB    32768
#define C_DIM   32
#define N_TOK   4096
#define OUT_N   (N_TOK * C_DIM)

#define SLICES   16
#define KPERSL   (K_CB / SLICES)     // 2048 codes per slice
#define TILE_N   256                 // codes per LDS tile
#define NTILES   (KPERSL / TILE_N)   // 8
#define TOK_TILE 64

// ---- async global->LDS (LDS dest = wave-uniform base + lane*size) ----
__device__ __forceinline__ void gl_lds16(const float* g, float* l) {
    __builtin_amdgcn_global_load_lds((const __attribute__((address_space(1))) void*)g,
                                     (__attribute__((address_space(3))) void*)l, 16, 0, 0);
}
__device__ __forceinline__ void gl_lds4(const float* g, float* l) {
    __builtin_amdgcn_global_load_lds((const __attribute__((address_space(1))) void*)g,
                                     (__attribute__((address_space(3))) void*)l, 4, 0, 0);
}

// ---------------------------------------------------------------------------
// Kernel A: transpose codebook [K][32] -> cbT[32][K], fused ||e_k||^2,
// and zero the loss cell (d_out is 0xAA-poisoned before every launch).
// ---------------------------------------------------------------------------
__global__ __launch_bounds__(256) void vq_cbT_norm(const float* __restrict__ cb,
                                                   float* __restrict__ cbT,
                                                   float* __restrict__ norms,
                                                   float* __restrict__ out) {
    __shared__ float tile[64][33];
    const int k0 = blockIdx.x * 64;
    const float4* src = reinterpret_cast<const float4*>(cb + (size_t)k0 * C_DIM);
#pragma unroll
    for (int i = 0; i < 2; ++i) {
        int f = threadIdx.x + i * 256;      // float4 index within 64x32 tile
        float4 v = src[f];
        int code = f >> 3, cq = (f & 7) * 4;
        tile[code][cq + 0] = v.x; tile[code][cq + 1] = v.y;
        tile[code][cq + 2] = v.z; tile[code][cq + 3] = v.w;
    }
    __syncthreads();
    // transposed write: thread (c, g) writes codes g*8..g*8+7 of channel c
    const int c = threadIdx.x >> 3;         // 0..31
    const int g = threadIdx.x & 7;          // 0..7
    float* dst = cbT + (size_t)c * K_CB + k0 + g * 8;
    float4 v0 = make_float4(tile[g*8+0][c], tile[g*8+1][c], tile[g*8+2][c], tile[g*8+3][c]);
    float4 v1 = make_float4(tile[g*8+4][c], tile[g*8+5][c], tile[g*8+6][c], tile[g*8+7][c]);
    *reinterpret_cast<float4*>(dst)     = v0;
    *reinterpret_cast<float4*>(dst + 4) = v1;
    // fused norms (threads 0..63, one code each; LDS banks (tt+cc)%32 distinct)
    if (threadIdx.x < 64) {
        const int tt = threadIdx.x;
        float s = 0.f;
#pragma unroll
        for (int cc = 0; cc < C_DIM; ++cc) { float v = tile[tt][cc]; s = fmaf(v, v, s); }
        norms[k0 + tt] = s;
    }
    if (blockIdx.x == 0 && threadIdx.x == 0) out[OUT_N] = 0.f;
}

// ---------------------------------------------------------------------------
// Kernel B: throughput argmin.  Block = 64 tokens x 2048-code slice,
// 256 threads; thread (tg,cg) owns 8 tokens x 8 codes (codes cg*4..+3 and
// 128+cg*4..+3 -> 16B lane stride on LDS reads = conflict-free).
// d' = ||e||^2 - 2 z.e  (per-token ||z||^2 dropped; argmin-equivalent).
// LDS exactly 40KB -> 4 blocks/CU -> all 1024 blocks resident.
// ---------------------------------------------------------------------------
__global__ __launch_bounds__(256, 4) void vq_partial(const float* __restrict__ z,
                                                     const float* __restrict__ cbT,
                                                     const float* __restrict__ cbnorm,
                                                     float* __restrict__ pdist,
                                                     int* __restrict__ pidx) {
    __shared__ __align__(16) float zt [C_DIM][TOK_TILE];  // 8 KB
    __shared__ __align__(16) float cbt[C_DIM][TILE_N];    // 32 KB

    const int tb   = blockIdx.x & 63;     // token tile
    const int ks   = blockIdx.x >> 6;     // k slice
    const int tok0 = tb * TOK_TILE;
    const int b    = tok0 >> 10;
    const int hw0  = tok0 & 1023;
    const int tid  = threadIdx.x;
    const int lane = tid & 63, wid = tid >> 6;
    const int cg   = tid & 31, tg  = tid >> 5;

    // stage z tile once: row c = 64 contiguous floats of z[b][c][hw0..]
    {
        const float* zb = z + (size_t)b * (C_DIM * 1024) + hw0 + lane;
        for (int c = wid * 8; c < wid * 8 + 8; ++c)
            gl_lds4(zb + (size_t)c * 1024, &zt[c][0]);
    }

    float best[8]; int bk[8];
#pragma unroll
    for (int m = 0; m < 8; ++m) { best[m] = INFINITY; bk[m] = 0; }

    const int k0s = ks * KPERSL;
    for (int t = 0; t < NTILES; ++t) {
        const int kt = k0s + t * TILE_N;
        for (int r = wid * 8; r < wid * 8 + 8; ++r)
            gl_lds16(cbT + (size_t)r * K_CB + kt + lane * 4, &cbt[r][0]);
        __syncthreads();   // vmcnt(0) drain -> tiles (and z on t==0) ready

        float acc[8][8];
#pragma unroll
        for (int m = 0; m < 8; ++m)
#pragma unroll
            for (int n = 0; n < 8; ++n) acc[m][n] = 0.f;

#pragma unroll 8
        for (int c = 0; c < C_DIM; ++c) {
            float4 za  = *reinterpret_cast<const float4*>(&zt[c][tg * 8]);      // half-wave bcast
            float4 zb4 = *reinterpret_cast<const float4*>(&zt[c][tg * 8 + 4]);
            float4 ea  = *reinterpret_cast<const float4*>(&cbt[c][cg * 4]);     // 16B lane stride
            float4 eb  = *reinterpret_cast<const float4*>(&cbt[c][128 + cg * 4]);
            float zr[8] = {za.x, za.y, za.z, za.w, zb4.x, zb4.y, zb4.z, zb4.w};
            float er[8] = {ea.x, ea.y, ea.z, ea.w, eb.x, eb.y, eb.z, eb.w};
#pragma unroll
            for (int m = 0; m < 8; ++m)
#pragma unroll
                for (int n = 0; n < 8; ++n)
                    acc[m][n] = fmaf(zr[m], er[n], acc[m][n]);
        }

        // norms straight from global (L2-resident, coalesced 16B/lane)
        float4 n0 = *reinterpret_cast<const float4*>(cbnorm + kt + cg * 4);
        float4 n1 = *reinterpret_cast<const float4*>(cbnorm + kt + 128 + cg * 4);
        float nr[8] = {n0.x, n0.y, n0.z, n0.w, n1.x, n1.y, n1.z, n1.w};
#pragma unroll
        for (int n = 0; n < 8; ++n) {         // k ascending in n => first-occurrence
            const int kk = kt + (n < 4 ? cg * 4 + n : 128 + cg * 4 + (n - 4));
#pragma unroll
            for (int m = 0; m < 8; ++m) {
                float d = fmaf(-2.f, acc[m][n], nr[n]);
                bool lt = d < best[m];
                best[m] = lt ? d : best[m];
                bk[m]   = lt ? kk : bk[m];
            }
        }
        __syncthreads();   // compute done before next tile overwrites cbt
    }

    // reduce over cg (32-lane halves); lexicographic (d,k)
#pragma unroll
    for (int off = 16; off > 0; off >>= 1) {
#pragma unroll
        for (int m = 0; m < 8; ++m) {
            float od = __shfl_xor(best[m], off, 64);
            int   ok = __shfl_xor(bk[m],   off, 64);
            bool take = (od < best[m]) || (od == best[m] && ok < bk[m]);
            best[m] = take ? od : best[m];
            bk[m]   = take ? ok : bk[m];
        }
    }
    if (cg == 0) {
#pragma unroll
        for (int m = 0; m < 8; ++m) {
            int tok = tok0 + tg * 8 + m;
            pdist[ks * N_TOK + tok] = best[m];
            pidx [ks * N_TOK + tok] = bk[m];
        }
    }
}

// ---------------------------------------------------------------------------
// Kernel C: merge slices, gather code, write zq (BCHW), loss.
// ---------------------------------------------------------------------------
__global__ __launch_bounds__(256) void vq_finalize(const float* __restrict__ z,
                                                   const float* __restrict__ cb,
                                                   const float* __restrict__ pdist,
                                                   const int* __restrict__ pidx,
                                                   float* __restrict__ out) {
    __shared__ float shd[4][64];
    __shared__ int   shk[4][64];
    __shared__ int   shbk[64];
    __shared__ float wsum[4];

    const int tok0 = blockIdx.x * 64;
    const int b = tok0 >> 10, hw0 = tok0 & 1023;
    const int tt = threadIdx.x & 63;   // token within tile
    const int sq = threadIdx.x >> 6;   // quarter
    const int tok = tok0 + tt;

    float bd = INFINITY; int bk = 0;
    for (int s = sq * 4; s < sq * 4 + 4; ++s) {
        float d = pdist[s * N_TOK + tok];
        int   k = pidx [s * N_TOK + tok];
        if (d < bd || (d == bd && k < bk)) { bd = d; bk = k; }
    }
    shd[sq][tt] = bd; shk[sq][tt] = bk;
    __syncthreads();
    if (threadIdx.x < 64) {
        bd = shd[0][tt]; bk = shk[0][tt];
        for (int q = 1; q < 4; ++q) {
            float d = shd[q][tt]; int k = shk[q][tt];
            if (d < bd || (d == bd && k < bk)) { bd = d; bk = k; }
        }
        shbk[tt] = bk;
    }
    __syncthreads();

    const int k = shbk[tt];
    const int c0 = sq * 8;
    const float* zp = z   + (size_t)b * (C_DIM * 1024) + hw0 + tt;
    float*       op = out + (size_t)b * (C_DIM * 1024) + hw0 + tt;
    float lsum = 0.f;
#pragma unroll
    for (int c = 0; c < 8; ++c) {
        float e  = cb[(size_t)k * C_DIM + c0 + c];
        float zc = zp[(size_t)(c0 + c) * 1024];
        float df = e - zc;
        lsum = fmaf(df, df, lsum);
        op[(size_t)(c0 + c) * 1024] = e;
    }

#pragma unroll
    for (int off = 32; off > 0; off >>= 1) lsum += __shfl_down(lsum, off, 64);
    const int lane = threadIdx.x & 63, wid = threadIdx.x >> 6;
    if (lane == 0) wsum[wid] = lsum;
    __syncthreads();
    if (threadIdx.x == 0)
        atomicAdd(out + OUT_N, (wsum[0] + wsum[1] + wsum[2] + wsum[3]) * (1.25f / (float)OUT_N));
}

// ---------------------------------------------------------------------------
extern "C" void kernel_launch(void* const* d_in, const int* in_sizes, int n_in,
                              void* d_out, int out_size, void* d_ws, size_t ws_size,
                              hipStream_t stream) {
    const float* z  = (const float*)d_in[0];
    const float* cb = (const float*)d_in[1];
    float* out = (float*)d_out;

    float* cbT   = (float*)d_ws;                    // 32*32768 f32 (4 MB)
    float* norms = cbT + (size_t)C_DIM * K_CB;      // 32768 f32  (128 KB)
    float* pdist = norms + K_CB;                    // 16*4096 f32 (256 KB)
    int*   pidx  = (int*)(pdist + SLICES * N_TOK);  // 16*4096 i32 (256 KB)

    vq_cbT_norm<<<K_CB / 64, 256, 0, stream>>>(cb, cbT, norms, out);
    vq_partial <<<(N_TOK / TOK_TILE) * SLICES, 256, 0, stream>>>(z, cbT, norms, pdist, pidx);
    vq_finalize<<<N_TOK / 64, 256, 0, stream>>>(z, cb, pdist, pidx, out);
}

// Round 6
// 175.768 us; speedup vs baseline: 2.6569x; 1.1356x over previous
//
#include <hip/hip_runtime.h>
#include <math.h>

#define K_CB    32768
#define C_DIM   32
#define N_TOK   4096
#define OUT_N   (N_TOK * C_DIM)

#define SLICES   16
#define KPERSL   (K_CB / SLICES)     // 2048 codes per slice
#define TILE_N   256                 // codes per LDS tile
#define NTILES   (KPERSL / TILE_N)   // 8
#define TOK_TILE 64

// ---- async global->LDS (LDS dest = wave-uniform base + lane*size) ----
__device__ __forceinline__ void gl_lds16(const float* g, float* l) {
    __builtin_amdgcn_global_load_lds((const __attribute__((address_space(1))) void*)g,
                                     (__attribute__((address_space(3))) void*)l, 16, 0, 0);
}
__device__ __forceinline__ void gl_lds4(const float* g, float* l) {
    __builtin_amdgcn_global_load_lds((const __attribute__((address_space(1))) void*)g,
                                     (__attribute__((address_space(3))) void*)l, 4, 0, 0);
}

// ---------------------------------------------------------------------------
// Kernel A: transpose codebook [K][32] -> cbT[32][K], fused ||e_k||^2,
// and zero the loss cell (d_out is 0xAA-poisoned before every launch).
// ---------------------------------------------------------------------------
__global__ __launch_bounds__(256) void vq_cbT_norm(const float* __restrict__ cb,
                                                   float* __restrict__ cbT,
                                                   float* __restrict__ norms,
                                                   float* __restrict__ out) {
    __shared__ float tile[64][33];
    const int k0 = blockIdx.x * 64;
    const float4* src = reinterpret_cast<const float4*>(cb + (size_t)k0 * C_DIM);
#pragma unroll
    for (int i = 0; i < 2; ++i) {
        int f = threadIdx.x + i * 256;      // float4 index within 64x32 tile
        float4 v = src[f];
        int code = f >> 3, cq = (f & 7) * 4;
        tile[code][cq + 0] = v.x; tile[code][cq + 1] = v.y;
        tile[code][cq + 2] = v.z; tile[code][cq + 3] = v.w;
    }
    __syncthreads();
    // transposed write: thread (c, g) writes codes g*8..g*8+7 of channel c
    const int c = threadIdx.x >> 3;         // 0..31
    const int g = threadIdx.x & 7;          // 0..7
    float* dst = cbT + (size_t)c * K_CB + k0 + g * 8;
    float4 v0 = make_float4(tile[g*8+0][c], tile[g*8+1][c], tile[g*8+2][c], tile[g*8+3][c]);
    float4 v1 = make_float4(tile[g*8+4][c], tile[g*8+5][c], tile[g*8+6][c], tile[g*8+7][c]);
    *reinterpret_cast<float4*>(dst)     = v0;
    *reinterpret_cast<float4*>(dst + 4) = v1;
    // fused norms (threads 0..63, one code each; LDS banks (tt+cc)%32 distinct)
    if (threadIdx.x < 64) {
        const int tt = threadIdx.x;
        float s = 0.f;
#pragma unroll
        for (int cc = 0; cc < C_DIM; ++cc) { float v = tile[tt][cc]; s = fmaf(v, v, s); }
        norms[k0 + tt] = s;
    }
    if (blockIdx.x == 0 && threadIdx.x == 0) out[OUT_N] = 0.f;
}

// ---------------------------------------------------------------------------
// Kernel B: throughput argmin.  Block = 64 tokens x 2048-code slice,
// 256 threads; thread (tg,cg) owns 8 tokens x 8 codes (codes cg*4..+3 and
// 128+cg*4..+3 -> 16B lane stride on LDS reads = conflict-free).
// d' = ||e||^2 - 2 z.e  (per-token ||z||^2 dropped; argmin-equivalent).
// LDS exactly 40KB -> 4 blocks/CU when VGPR<=128.
// NOTE: no min-waves clamp — __launch_bounds__(256,4) made the allocator
// squeeze to the 64-VGPR breakpoint and spill acc[8][8] (77MB scratch
// writes in R4 profile). unroll 2 keeps operand live-range ~115 regs.
// ---------------------------------------------------------------------------
__global__ __launch_bounds__(256) void vq_partial(const float* __restrict__ z,
                                                  const float* __restrict__ cbT,
                                                  const float* __restrict__ cbnorm,
                                                  float* __restrict__ pdist,
                                                  int* __restrict__ pidx) {
    __shared__ __align__(16) float zt [C_DIM][TOK_TILE];  // 8 KB
    __shared__ __align__(16) float cbt[C_DIM][TILE_N];    // 32 KB

    const int tb   = blockIdx.x & 63;     // token tile
    const int ks   = blockIdx.x >> 6;     // k slice
    const int tok0 = tb * TOK_TILE;
    const int b    = tok0 >> 10;
    const int hw0  = tok0 & 1023;
    const int tid  = threadIdx.x;
    const int lane = tid & 63, wid = tid >> 6;
    const int cg   = tid & 31, tg  = tid >> 5;

    // stage z tile once: row c = 64 contiguous floats of z[b][c][hw0..]
    {
        const float* zb = z + (size_t)b * (C_DIM * 1024) + hw0 + lane;
        for (int c = wid * 8; c < wid * 8 + 8; ++c)
            gl_lds4(zb + (size_t)c * 1024, &zt[c][0]);
    }

    float best[8]; int bk[8];
#pragma unroll
    for (int m = 0; m < 8; ++m) { best[m] = INFINITY; bk[m] = 0; }

    const int k0s = ks * KPERSL;
    for (int t = 0; t < NTILES; ++t) {
        const int kt = k0s + t * TILE_N;
        for (int r = wid * 8; r < wid * 8 + 8; ++r)
            gl_lds16(cbT + (size_t)r * K_CB + kt + lane * 4, &cbt[r][0]);
        __syncthreads();   // vmcnt(0) drain -> tiles (and z on t==0) ready

        float acc[8][8];
#pragma unroll
        for (int m = 0; m < 8; ++m)
#pragma unroll
            for (int n = 0; n < 8; ++n) acc[m][n] = 0.f;

#pragma unroll 2
        for (int c = 0; c < C_DIM; ++c) {
            float4 za  = *reinterpret_cast<const float4*>(&zt[c][tg * 8]);      // half-wave bcast
            float4 zb4 = *reinterpret_cast<const float4*>(&zt[c][tg * 8 + 4]);
            float4 ea  = *reinterpret_cast<const float4*>(&cbt[c][cg * 4]);     // 16B lane stride
            float4 eb  = *reinterpret_cast<const float4*>(&cbt[c][128 + cg * 4]);
            float zr[8] = {za.x, za.y, za.z, za.w, zb4.x, zb4.y, zb4.z, zb4.w};
            float er[8] = {ea.x, ea.y, ea.z, ea.w, eb.x, eb.y, eb.z, eb.w};
#pragma unroll
            for (int m = 0; m < 8; ++m)
#pragma unroll
                for (int n = 0; n < 8; ++n)
                    acc[m][n] = fmaf(zr[m], er[n], acc[m][n]);
        }

        // norms straight from global (L2-resident, coalesced 16B/lane)
        float4 n0 = *reinterpret_cast<const float4*>(cbnorm + kt + cg * 4);
        float4 n1 = *reinterpret_cast<const float4*>(cbnorm + kt + 128 + cg * 4);
        float nr[8] = {n0.x, n0.y, n0.z, n0.w, n1.x, n1.y, n1.z, n1.w};
#pragma unroll
        for (int n = 0; n < 8; ++n) {         // k ascending in n => first-occurrence
            const int kk = kt + (n < 4 ? cg * 4 + n : 128 + cg * 4 + (n - 4));
#pragma unroll
            for (int m = 0; m < 8; ++m) {
                float d = fmaf(-2.f, acc[m][n], nr[n]);
                bool lt = d < best[m];
                best[m] = lt ? d : best[m];
                bk[m]   = lt ? kk : bk[m];
            }
        }
        __syncthreads();   // compute done before next tile overwrites cbt
    }

    // reduce over cg (32-lane halves); lexicographic (d,k)
#pragma unroll
    for (int off = 16; off > 0; off >>= 1) {
#pragma unroll
        for (int m = 0; m < 8; ++m) {
            float od = __shfl_xor(best[m], off, 64);
            int   ok = __shfl_xor(bk[m],   off, 64);
            bool take = (od < best[m]) || (od == best[m] && ok < bk[m]);
            best[m] = take ? od : best[m];
            bk[m]   = take ? ok : bk[m];
        }
    }
    if (cg == 0) {
#pragma unroll
        for (int m = 0; m < 8; ++m) {
            int tok = tok0 + tg * 8 + m;
            pdist[ks * N_TOK + tok] = best[m];
            pidx [ks * N_TOK + tok] = bk[m];
        }
    }
}

// ---------------------------------------------------------------------------
// Kernel C: merge slices, gather code, write zq (BCHW), loss.
// ---------------------------------------------------------------------------
__global__ __launch_bounds__(256) void vq_finalize(const float* __restrict__ z,
                                                   const float* __restrict__ cb,
                                                   const float* __restrict__ pdist,
                                                   const int* __restrict__ pidx,
                                                   float* __restrict__ out) {
    __shared__ float shd[4][64];
    __shared__ int   shk[4][64];
    __shared__ int   shbk[64];
    __shared__ float wsum[4];

    const int tok0 = blockIdx.x * 64;
    const int b = tok0 >> 10, hw0 = tok0 & 1023;
    const int tt = threadIdx.x & 63;   // token within tile
    const int sq = threadIdx.x >> 6;   // quarter
    const int tok = tok0 + tt;

    float bd = INFINITY; int bk = 0;
    for (int s = sq * 4; s < sq * 4 + 4; ++s) {
        float d = pdist[s * N_TOK + tok];
        int   k = pidx [s * N_TOK + tok];
        if (d < bd || (d == bd && k < bk)) { bd = d; bk = k; }
    }
    shd[sq][tt] = bd; shk[sq][tt] = bk;
    __syncthreads();
    if (threadIdx.x < 64) {
        bd = shd[0][tt]; bk = shk[0][tt];
        for (int q = 1; q < 4; ++q) {
            float d = shd[q][tt]; int k = shk[q][tt];
            if (d < bd || (d == bd && k < bk)) { bd = d; bk = k; }
        }
        shbk[tt] = bk;
    }
    __syncthreads();

    const int k = shbk[tt];
    const int c0 = sq * 8;
    const float* zp = z   + (size_t)b * (C_DIM * 1024) + hw0 + tt;
    float*       op = out + (size_t)b * (C_DIM * 1024) + hw0 + tt;
    float lsum = 0.f;
#pragma unroll
    for (int c = 0; c < 8; ++c) {
        float e  = cb[(size_t)k * C_DIM + c0 + c];
        float zc = zp[(size_t)(c0 + c) * 1024];
        float df = e - zc;
        lsum = fmaf(df, df, lsum);
        op[(size_t)(c0 + c) * 1024] = e;
    }

#pragma unroll
    for (int off = 32; off > 0; off >>= 1) lsum += __shfl_down(lsum, off, 64);
    const int lane = threadIdx.x & 63, wid = threadIdx.x >> 6;
    if (lane == 0) wsum[wid] = lsum;
    __syncthreads();
    if (threadIdx.x == 0)
        atomicAdd(out + OUT_N, (wsum[0] + wsum[1] + wsum[2] + wsum[3]) * (1.25f / (float)OUT_N));
}

// ---------------------------------------------------------------------------
extern "C" void kernel_launch(void* const* d_in, const int* in_sizes, int n_in,
                              void* d_out, int out_size, void* d_ws, size_t ws_size,
                              hipStream_t stream) {
    const float* z  = (const float*)d_in[0];
    const float* cb = (const float*)d_in[1];
    float* out = (float*)d_out;

    float* cbT   = (float*)d_ws;                    // 32*32768 f32 (4 MB)
    float* norms = cbT + (size_t)C_DIM * K_CB;      // 32768 f32  (128 KB)
    float* pdist = norms + K_CB;                    // 16*4096 f32 (256 KB)
    int*   pidx  = (int*)(pdist + SLICES * N_TOK);  // 16*4096 i32 (256 KB)

    vq_cbT_norm<<<K_CB / 64, 256, 0, stream>>>(cb, cbT, norms, out);
    vq_partial <<<(N_TOK / TOK_TILE) * SLICES, 256, 0, stream>>>(z, cbT, norms, pdist, pidx);
    vq_finalize<<<N_TOK / 64, 256, 0, stream>>>(z, cb, pdist, pidx, out);
}

// Round 7
// 109.201 us; speedup vs baseline: 4.2766x; 1.6096x over previous
//
#include <hip/hip_runtime.h>
#include <math.h>

#define K_CB    32768
#define C_DIM   32
#define N_TOK   4096
#define OUT_N   (N_TOK * C_DIM)

#define SLICES  32
#define KPERSL  (K_CB / SLICES)    // 1024 codes per slice
#define GROUPS  (KPERSL / 16)      // 64 groups of 16 codes
#define SCALE   4096.0f            // 2^12 pre-scale (exact), kills fp16 subnormals

typedef _Float16 half8  __attribute__((ext_vector_type(8)));
typedef float    floatx4 __attribute__((ext_vector_type(4)));

// ---------------------------------------------------------------------------
// Kernel A: z [B][C][H][W] f32 -> token-major fp16 hi/lo pairs (scaled 2^12).
// hi = fp16(x*S); lo = fp16(x*S - hi). Residual < 2^-24 rel of x.
// ---------------------------------------------------------------------------
__global__ __launch_bounds__(256) void vq_zprep(const float* __restrict__ z,
                                                _Float16* __restrict__ zh,
                                                _Float16* __restrict__ zl) {
    const int tok = blockIdx.x * 256 + threadIdx.x;
    const int b = tok >> 10, hw = tok & 1023;
    const float* zp = z + (size_t)b * (C_DIM * 1024) + hw;
    _Float16 h[C_DIM], l[C_DIM];
#pragma unroll
    for (int c = 0; c < C_DIM; ++c) {
        float xs = zp[(size_t)c * 1024] * SCALE;   // coalesced per-c across lanes
        _Float16 hh = (_Float16)xs;
        h[c] = hh;
        l[c] = (_Float16)(xs - (float)hh);
    }
    half8* dh = (half8*)(zh + (size_t)tok * C_DIM);
    half8* dl = (half8*)(zl + (size_t)tok * C_DIM);
#pragma unroll
    for (int i = 0; i < 4; ++i) {
        dh[i] = *(half8*)&h[i * 8];
        dl[i] = *(half8*)&l[i * 8];
    }
}

// ---------------------------------------------------------------------------
// Kernel B: codebook [K][32] f32 -> fp16 hi/lo (scaled) + fp32 ||e||^2.
// Also zeroes the loss cell (d_out is 0xAA-poisoned every launch).
// ---------------------------------------------------------------------------
__global__ __launch_bounds__(256) void vq_cbprep(const float* __restrict__ cb,
                                                 _Float16* __restrict__ ch,
                                                 _Float16* __restrict__ cl,
                                                 float* __restrict__ nrm,
                                                 float* __restrict__ out) {
    const int k = blockIdx.x * 256 + threadIdx.x;
    const float4* src = (const float4*)(cb + (size_t)k * C_DIM);
    _Float16 h[C_DIM], l[C_DIM];
    float s = 0.f;
#pragma unroll
    for (int i = 0; i < 8; ++i) {
        float4 v = src[i];
        s = fmaf(v.x, v.x, s); s = fmaf(v.y, v.y, s);
        s = fmaf(v.z, v.z, s); s = fmaf(v.w, v.w, s);
        float x[4] = {v.x * SCALE, v.y * SCALE, v.z * SCALE, v.w * SCALE};
#pragma unroll
        for (int j = 0; j < 4; ++j) {
            _Float16 hh = (_Float16)x[j];
            h[i * 4 + j] = hh;
            l[i * 4 + j] = (_Float16)(x[j] - (float)hh);
        }
    }
    nrm[k] = s;
    half8* dh = (half8*)(ch + (size_t)k * C_DIM);
    half8* dl = (half8*)(cl + (size_t)k * C_DIM);
#pragma unroll
    for (int i = 0; i < 4; ++i) {
        dh[i] = *(half8*)&h[i * 8];
        dl[i] = *(half8*)&l[i * 8];
    }
    if (k == 0) out[OUT_N] = 0.f;
}

// ---------------------------------------------------------------------------
// Kernel C: MFMA argmin.  acc = z.e*2^24 - nrm*2^23 via 3 fp16 MFMAs
// (hi.hi + hi.lo + lo.hi; lo.lo ~2e-6 in d-units, below fp32 matmul noise).
// argmin d == argmax acc.  Wave = 2 strips x 16 tokens, 1024-code slice.
// Fragment layout (m90-97 verified): both operands lane&15 = matrix row,
// k = (lane>>4)*8..+8; D: col(code)=lane&15, row(token)=(lane>>4)*4+reg.
// ---------------------------------------------------------------------------
__global__ __launch_bounds__(256) void vq_mfma(const _Float16* __restrict__ zh,
                                               const _Float16* __restrict__ zl,
                                               const _Float16* __restrict__ ch,
                                               const _Float16* __restrict__ cl,
                                               const float* __restrict__ nrm,
                                               float* __restrict__ pdist,
                                               int* __restrict__ pidx) {
    const int tid   = threadIdx.x;
    const int lane  = tid & 63, wid = tid >> 6;
    const int row16 = lane & 15, kgrp = lane >> 4;
    const int tile  = blockIdx.x & 31;    // token tile (128 tokens)
    const int slice = blockIdx.x >> 5;    // code slice (1024 codes)
    const int tokA  = tile * 128 + wid * 32 + row16;   // strip 0
    const int code0 = slice * KPERSL;

    // A fragments (held for whole kernel): 2 strips x (hi,lo)
    const half8 a0h = *(const half8*)(zh + (size_t)tokA * C_DIM + kgrp * 8);
    const half8 a0l = *(const half8*)(zl + (size_t)tokA * C_DIM + kgrp * 8);
    const half8 a1h = *(const half8*)(zh + (size_t)(tokA + 16) * C_DIM + kgrp * 8);
    const half8 a1l = *(const half8*)(zl + (size_t)(tokA + 16) * C_DIM + kgrp * 8);

    const _Float16* pbh = ch + (size_t)(code0 + row16) * C_DIM + kgrp * 8;
    const _Float16* pbl = cl + (size_t)(code0 + row16) * C_DIM + kgrp * 8;
    const float*    pn  = nrm + code0 + row16;
    int kc = code0 + row16;               // this lane's code id, +16 per group

    float best0[4], best1[4]; int bk0[4], bk1[4];
#pragma unroll
    for (int j = 0; j < 4; ++j) {
        best0[j] = -INFINITY; best1[j] = -INFINITY; bk0[j] = 0; bk1[j] = 0;
    }

#pragma unroll 2
    for (int g = 0; g < GROUPS; ++g) {
        half8 bh = *(const half8*)pbh;    // 16 codes hi-fragment (1KB/wave, coalesced)
        half8 bl = *(const half8*)pbl;
        float nv = *pn;
        float initv = nv * -8388608.0f;   // -nrm/2 * 2^24
        floatx4 acc0 = {initv, initv, initv, initv};
        floatx4 acc1 = acc0;
        acc0 = __builtin_amdgcn_mfma_f32_16x16x32_f16(a0h, bl, acc0, 0, 0, 0);
        acc1 = __builtin_amdgcn_mfma_f32_16x16x32_f16(a1h, bl, acc1, 0, 0, 0);
        acc0 = __builtin_amdgcn_mfma_f32_16x16x32_f16(a0l, bh, acc0, 0, 0, 0);
        acc1 = __builtin_amdgcn_mfma_f32_16x16x32_f16(a1l, bh, acc1, 0, 0, 0);
        acc0 = __builtin_amdgcn_mfma_f32_16x16x32_f16(a0h, bh, acc0, 0, 0, 0);
        acc1 = __builtin_amdgcn_mfma_f32_16x16x32_f16(a1h, bh, acc1, 0, 0, 0);
#pragma unroll
        for (int j = 0; j < 4; ++j) {     // strict > keeps first (lowest k) on ties
            float s0 = acc0[j];
            bool g0 = s0 > best0[j];
            best0[j] = g0 ? s0 : best0[j];
            bk0[j]   = g0 ? kc : bk0[j];
            float s1 = acc1[j];
            bool g1 = s1 > best1[j];
            best1[j] = g1 ? s1 : best1[j];
            bk1[j]   = g1 ? kc : bk1[j];
        }
        pbh += 16 * C_DIM; pbl += 16 * C_DIM; pn += 16; kc += 16;
    }

    // reduce across the 16 code-columns (low 4 lane bits); lexicographic
    // (max acc, then min k)
#pragma unroll
    for (int off = 1; off < 16; off <<= 1) {
#pragma unroll
        for (int j = 0; j < 4; ++j) {
            float os = __shfl_xor(best0[j], off, 64);
            int   ok = __shfl_xor(bk0[j],   off, 64);
            bool t = (os > best0[j]) || (os == best0[j] && ok < bk0[j]);
            best0[j] = t ? os : best0[j];
            bk0[j]   = t ? ok : bk0[j];
            os = __shfl_xor(best1[j], off, 64);
            ok = __shfl_xor(bk1[j],   off, 64);
            t = (os > best1[j]) || (os == best1[j] && ok < bk1[j]);
            best1[j] = t ? os : best1[j];
            bk1[j]   = t ? ok : bk1[j];
        }
    }

    if (row16 == 0) {
#pragma unroll
        for (int j = 0; j < 4; ++j) {
            int r  = kgrp * 4 + j;                    // D row = token within strip
            int t0 = tile * 128 + wid * 32 + r;
            pdist[slice * N_TOK + t0]      = best0[j] * -1.1920928955078125e-7f; // -2^-23, exact
            pidx [slice * N_TOK + t0]      = bk0[j];
            pdist[slice * N_TOK + t0 + 16] = best1[j] * -1.1920928955078125e-7f;
            pidx [slice * N_TOK + t0 + 16] = bk1[j];
        }
    }
}

// ---------------------------------------------------------------------------
// Kernel D: merge 32 slices, gather code, write zq (BCHW), loss.
// ---------------------------------------------------------------------------
__global__ __launch_bounds__(256) void vq_finalize(const float* __restrict__ z,
                                                   const float* __restrict__ cb,
                                                   const float* __restrict__ pdist,
                                                   const int* __restrict__ pidx,
                                                   float* __restrict__ out) {
    __shared__ float shd[4][64];
    __shared__ int   shk[4][64];
    __shared__ int   shbk[64];
    __shared__ float wsum[4];

    const int tok0 = blockIdx.x * 64;
    const int b = tok0 >> 10, hw0 = tok0 & 1023;
    const int tt = threadIdx.x & 63;   // token within tile
    const int sq = threadIdx.x >> 6;   // quarter
    const int tok = tok0 + tt;

    float bd = INFINITY; int bk = 0;
    for (int s = sq * 8; s < sq * 8 + 8; ++s) {        // ascending k ranges
        float d = pdist[s * N_TOK + tok];
        int   k = pidx [s * N_TOK + tok];
        if (d < bd || (d == bd && k < bk)) { bd = d; bk = k; }
    }
    shd[sq][tt] = bd; shk[sq][tt] = bk;
    __syncthreads();
    if (threadIdx.x < 64) {
        bd = shd[0][tt]; bk = shk[0][tt];
        for (int q = 1; q < 4; ++q) {                  // ascending k ranges
            float d = shd[q][tt]; int k = shk[q][tt];
            if (d < bd || (d == bd && k < bk)) { bd = d; bk = k; }
        }
        shbk[tt] = bk;
    }
    __syncthreads();

    const int k = shbk[tt];
    const int c0 = sq * 8;
    const float* zp = z   + (size_t)b * (C_DIM * 1024) + hw0 + tt;
    float*       op = out + (size_t)b * (C_DIM * 1024) + hw0 + tt;
    float lsum = 0.f;
#pragma unroll
    for (int c = 0; c < 8; ++c) {
        float e  = cb[(size_t)k * C_DIM + c0 + c];
        float zc = zp[(size_t)(c0 + c) * 1024];
        float df = e - zc;
        lsum = fmaf(df, df, lsum);
        op[(size_t)(c0 + c) * 1024] = e;
    }

#pragma unroll
    for (int off = 32; off > 0; off >>= 1) lsum += __shfl_down(lsum, off, 64);
    const int lane = threadIdx.x & 63, wid = threadIdx.x >> 6;
    if (lane == 0) wsum[wid] = lsum;
    __syncthreads();
    if (threadIdx.x == 0)
        atomicAdd(out + OUT_N, (wsum[0] + wsum[1] + wsum[2] + wsum[3]) * (1.25f / (float)OUT_N));
}

// ---------------------------------------------------------------------------
extern "C" void kernel_launch(void* const* d_in, const int* in_sizes, int n_in,
                              void* d_out, int out_size, void* d_ws, size_t ws_size,
                              hipStream_t stream) {
    const float* z  = (const float*)d_in[0];
    const float* cb = (const float*)d_in[1];
    float* out = (float*)d_out;

    // workspace: 5.625 MB total
    _Float16* zh = (_Float16*)d_ws;                       // 256 KB
    _Float16* zl = zh + (size_t)N_TOK * C_DIM;            // 256 KB
    _Float16* ch = zl + (size_t)N_TOK * C_DIM;            // 2 MB
    _Float16* cl = ch + (size_t)K_CB * C_DIM;             // 2 MB
    float*  norms = (float*)(cl + (size_t)K_CB * C_DIM);  // 128 KB
    float*  pdist = norms + K_CB;                         // 512 KB
    int*    pidx  = (int*)(pdist + SLICES * N_TOK);       // 512 KB

    vq_zprep   <<<N_TOK / 256, 256, 0, stream>>>(z, zh, zl);
    vq_cbprep  <<<K_CB / 256, 256, 0, stream>>>(cb, ch, cl, norms, out);
    vq_mfma    <<<(N_TOK / 128) * SLICES, 256, 0, stream>>>(zh, zl, ch, cl, norms, pdist, pidx);
    vq_finalize<<<N_TOK / 64, 256, 0, stream>>>(z, cb, pdist, pidx, out);
}